// Round 1
// baseline (103.072 us; speedup 1.0000x reference)
//
#include <hip/hip_runtime.h>
#include <hip/hip_bf16.h>
#include <math.h>

typedef __attribute__((ext_vector_type(8))) short short8;
typedef __attribute__((ext_vector_type(4))) float f32x4;
typedef __attribute__((ext_vector_type(4))) unsigned int u32x4;

#define NPT 1024
#define D   128

__device__ __forceinline__ unsigned short f2bf(float f) {
  __hip_bfloat16 h = __float2bfloat16(f);
  return __builtin_bit_cast(unsigned short, h);
}

// ---------------- kernel 1: xwg = x @ Wg (f32) -> ws ----------------
__global__ __launch_bounds__(128) void k_xwg(const float* __restrict__ x,
                                             const float* __restrict__ Wg,
                                             float* __restrict__ xwg) {
  __shared__ float xi[D];
  const int i = blockIdx.x;
  const int t = threadIdx.x;
  xi[t] = x[i * D + t];
  __syncthreads();
  float acc = 0.f;
#pragma unroll 8
  for (int k = 0; k < D; ++k) acc += xi[k] * Wg[k * D + t];
  xwg[i * D + t] = acc;
}

// ---------------- kernel 2: adjacency via bf16 MFMA ----------------
// 256 blocks x 512 threads. Each block: 4 i-rows, all 1024 j.
// LDS: W1^T bf16 swizzled (32KB) + x-chunk bf16 swizzled (16KB) + xi f32 (2KB)
__global__ __launch_bounds__(512, 2) void k_adj(const float* __restrict__ x,
                                                const float* __restrict__ W1,
                                                const float* __restrict__ b1,
                                                const float* __restrict__ W2,
                                                const float* __restrict__ b2,
                                                float* __restrict__ adj) {
  __shared__ unsigned short w1t[128 * 128]; // (hid,k) at byte hid*256 + (2k ^ ((hid&7)<<4))
  __shared__ unsigned short xch[64 * 128];  // (row,k) at byte row*256 + (2k ^ ((row&7)<<4))
  __shared__ float xil[4 * 128];

  const int tid  = threadIdx.x;
  const int lane = tid & 63;
  const int w    = tid >> 6;   // wave 0..7
  const int l15  = lane & 15;
  const int g    = lane >> 4;  // 0..3
  const int ibase = blockIdx.x * 4;

  // stage W1^T (bf16, swizzled)
  for (int idx = tid; idx < 128 * 128; idx += 512) {
    const int k = idx >> 7, hid = idx & 127;
    const unsigned short v = f2bf(W1[idx]);
    const int byte = hid * 256 + ((2 * k) ^ ((hid & 7) << 4));
    *(unsigned short*)((char*)w1t + byte) = v;
  }
  // stage 4 xi rows (f32, linear)
  {
    const int r = tid >> 7, c = tid & 127;
    xil[tid] = x[(ibase + r) * D + c];
  }
  __syncthreads();

  // preload B fragments into registers: bf[ks][ht], k = 32*ks + 8*g + e
  short8 bfrag[4][8];
#pragma unroll
  for (int ks = 0; ks < 4; ++ks)
#pragma unroll
    for (int ht = 0; ht < 8; ++ht) {
      const int hid = ht * 16 + l15;
      const int k0 = ks * 32 + g * 8;
      const int byte = hid * 256 + ((2 * k0) ^ ((hid & 7) << 4));
      bfrag[ks][ht] = *(const short8*)((const char*)w1t + byte);
    }
  float b1v[8], w2v[8];
#pragma unroll
  for (int ht = 0; ht < 8; ++ht) {
    b1v[ht] = b1[ht * 16 + l15];
    w2v[ht] = W2[ht * 16 + l15];
  }
  const float b2s = b2[0];
  const int jsub = w & 3;

  for (int jc = 0; jc < 16; ++jc) {
    __syncthreads(); // previous chunk's compute done before overwrite
    // stage 64 rows of x as bf16, swizzled: 512 thr x 2 iters x 8 elems
#pragma unroll
    for (int it = 0; it < 2; ++it) {
      const int row = it * 32 + (tid >> 4);
      const int col = (tid & 15) * 8;
      const float* src = &x[(jc * 64 + row) * D + col];
      const f32x4 v0 = *(const f32x4*)(src);
      const f32x4 v1 = *(const f32x4*)(src + 4);
      short8 pk;
#pragma unroll
      for (int e = 0; e < 4; ++e) pk[e] = (short)f2bf(v0[e]);
#pragma unroll
      for (int e = 0; e < 4; ++e) pk[4 + e] = (short)f2bf(v1[e]);
      const int byte = row * 256 + ((2 * col) ^ ((row & 7) << 4));
      *(short8*)((char*)xch + byte) = pk;
    }
    __syncthreads();

#pragma unroll
    for (int half = 0; half < 2; ++half) {
      const int iloc = (w >> 2) * 2 + half;
      const int i = ibase + iloc;
      f32x4 acc[8];
#pragma unroll
      for (int ht = 0; ht < 8; ++ht)
        acc[ht] = f32x4{b1v[ht], b1v[ht], b1v[ht], b1v[ht]};

#pragma unroll
      for (int ks = 0; ks < 4; ++ks) {
        const int k0 = ks * 32 + g * 8;
        const f32x4 xa = *(const f32x4*)&xil[iloc * D + k0];
        const f32x4 xb = *(const f32x4*)&xil[iloc * D + k0 + 4];
        const int row = jsub * 16 + l15;
        const int byte = row * 256 + ((2 * k0) ^ ((row & 7) << 4));
        const u32x4 jr = *(const u32x4*)((const char*)xch + byte);
        short8 af;
#pragma unroll
        for (int p = 0; p < 4; ++p) {
          const float lo = __builtin_bit_cast(float, jr[p] << 16);
          const float hi = __builtin_bit_cast(float, jr[p] & 0xffff0000u);
          const float xlo = (p < 2) ? xa[2 * p]     : xb[2 * (p - 2)];
          const float xhi = (p < 2) ? xa[2 * p + 1] : xb[2 * (p - 2) + 1];
          af[2 * p]     = (short)f2bf(fabsf(xlo - lo));
          af[2 * p + 1] = (short)f2bf(fabsf(xhi - hi));
        }
#pragma unroll
        for (int ht = 0; ht < 8; ++ht)
          acc[ht] = __builtin_amdgcn_mfma_f32_16x16x32_bf16(af, bfrag[ks][ht],
                                                            acc[ht], 0, 0, 0);
      }
      // epilogue: relu, dot W2, 16-lane reduce, sigmoid, store
      float s0 = 0.f, s1 = 0.f, s2 = 0.f, s3 = 0.f;
#pragma unroll
      for (int ht = 0; ht < 8; ++ht) {
        s0 += fmaxf(acc[ht][0], 0.f) * w2v[ht];
        s1 += fmaxf(acc[ht][1], 0.f) * w2v[ht];
        s2 += fmaxf(acc[ht][2], 0.f) * w2v[ht];
        s3 += fmaxf(acc[ht][3], 0.f) * w2v[ht];
      }
#pragma unroll
      for (int m = 1; m <= 8; m <<= 1) {
        s0 += __shfl_xor(s0, m);
        s1 += __shfl_xor(s1, m);
        s2 += __shfl_xor(s2, m);
        s3 += __shfl_xor(s3, m);
      }
      if (l15 == 0) {
        f32x4 st;
        st[0] = 1.f / (1.f + __expf(-(s0 + b2s)));
        st[1] = 1.f / (1.f + __expf(-(s1 + b2s)));
        st[2] = 1.f / (1.f + __expf(-(s2 + b2s)));
        st[3] = 1.f / (1.f + __expf(-(s3 + b2s)));
        const int j = jc * 64 + jsub * 16 + g * 4;
        *(f32x4*)&adj[i * NPT + j] = st;
      }
    }
  }
}

// ---------------- kernel 3: dinv = rsqrt(rowsum(adj)) ----------------
__global__ __launch_bounds__(256) void k_deg(const float* __restrict__ adj,
                                             float* __restrict__ dinv) {
  __shared__ float red[4];
  const int i = blockIdx.x;
  const int tid = threadIdx.x;
  const f32x4 v = ((const f32x4*)&adj[i * NPT])[tid];
  float s = v[0] + v[1] + v[2] + v[3];
#pragma unroll
  for (int m = 1; m < 64; m <<= 1) s += __shfl_xor(s, m);
  if ((tid & 63) == 0) red[tid >> 6] = s;
  __syncthreads();
  if (tid == 0) dinv[i] = rsqrtf(red[0] + red[1] + red[2] + red[3]);
}

// ---------------- kernel 4: zero out-region ----------------
__global__ void k_zero(float* __restrict__ p) {
  p[blockIdx.x * 256 + threadIdx.x] = 0.f;
}

// ---------------- kernel 5: partial = sum_j (adj*dinv_j) * xwg, atomic ----------------
__global__ __launch_bounds__(256) void k_d1(const float* __restrict__ adj,
                                            const float* __restrict__ xwg,
                                            const float* __restrict__ dinv,
                                            float* __restrict__ outp) {
  __shared__ float ysh[64 * 128];
  __shared__ float anT[64 * 36];
  const int tid = threadIdx.x;
  const int i0 = blockIdx.x * 32;
  const int jbase = blockIdx.y * 128;
  const int iq = tid >> 5;  // 0..7
  const int tq = tid & 31;  // t0 = tq*4
  float acc[4][4];
#pragma unroll
  for (int a = 0; a < 4; ++a)
#pragma unroll
    for (int b = 0; b < 4; ++b) acc[a][b] = 0.f;

  for (int ch = 0; ch < 2; ++ch) {
    const int jb = jbase + ch * 64;
    __syncthreads();
#pragma unroll
    for (int it = 0; it < 8; ++it) {
      const int row = it * 8 + (tid >> 5);
      const int col = (tid & 31) * 4;
      *(f32x4*)&ysh[row * 128 + col] = *(const f32x4*)&xwg[(jb + row) * 128 + col];
    }
#pragma unroll
    for (int it = 0; it < 8; ++it) {
      const int ii = it * 4 + (tid >> 6);
      const int jj = tid & 63;
      anT[jj * 36 + ii] = adj[(i0 + ii) * NPT + jb + jj] * dinv[jb + jj];
    }
    __syncthreads();
#pragma unroll 4
    for (int jj = 0; jj < 64; ++jj) {
      const f32x4 yv = *(const f32x4*)&ysh[jj * 128 + tq * 4];
      const f32x4 an4 = *(const f32x4*)&anT[jj * 36 + iq * 4];
#pragma unroll
      for (int a = 0; a < 4; ++a)
#pragma unroll
        for (int b = 0; b < 4; ++b) acc[a][b] += an4[a] * yv[b];
    }
  }
#pragma unroll
  for (int a = 0; a < 4; ++a)
#pragma unroll
    for (int b = 0; b < 4; ++b)
      atomicAdd(&outp[(i0 + iq * 4 + a) * D + tq * 4 + b], acc[a][b]);
}

// ---------------- kernel 6: out = leaky(dinv_i * partial + bg) ----------------
__global__ void k_d2(float* __restrict__ outp, const float* __restrict__ dinv,
                     const float* __restrict__ bg) {
  const int idx = blockIdx.x * 256 + threadIdx.x;
  const int i = idx >> 7, t = idx & 127;
  const float v = outp[idx] * dinv[i] + bg[t];
  outp[idx] = v > 0.f ? v : 0.2f * v;
}

extern "C" void kernel_launch(void* const* d_in, const int* in_sizes, int n_in,
                              void* d_out, int out_size, void* d_ws, size_t ws_size,
                              hipStream_t stream) {
  const float* x  = (const float*)d_in[0];
  const float* W1 = (const float*)d_in[1];
  const float* b1 = (const float*)d_in[2];
  const float* W2 = (const float*)d_in[3];
  const float* b2 = (const float*)d_in[4];
  const float* Wg = (const float*)d_in[5];
  const float* bg = (const float*)d_in[6];

  float* outp = (float*)d_out;            // [1024*128]
  float* adj  = outp + NPT * D;           // [1024*1024]
  float* xwg  = (float*)d_ws;             // [1024*128]
  float* dinv = xwg + NPT * D;            // [1024]

  k_xwg<<<NPT, 128, 0, stream>>>(x, Wg, xwg);
  k_adj<<<256, 512, 0, stream>>>(x, W1, b1, W2, b2, adj);
  k_deg<<<NPT, 256, 0, stream>>>(adj, dinv);
  k_zero<<<512, 256, 0, stream>>>(outp);
  k_d1<<<dim3(32, 8), 256, 0, stream>>>(adj, xwg, dinv, outp);
  k_d2<<<512, 256, 0, stream>>>(outp, dinv, bg);
}

// Round 2
// 101.135 us; speedup vs baseline: 1.0192x; 1.0192x over previous
//
#include <hip/hip_runtime.h>
#include <hip/hip_bf16.h>
#include <math.h>

typedef __attribute__((ext_vector_type(8))) short short8;
typedef __attribute__((ext_vector_type(4))) float f32x4;
typedef __attribute__((ext_vector_type(4))) unsigned int u32x4;

#define NPT 1024
#define D   128

__device__ __forceinline__ unsigned short f2bf(float f) {
  __hip_bfloat16 h = __float2bfloat16(f);
  return __builtin_bit_cast(unsigned short, h);
}

// ---------------- kernel 1: xwg = x @ Wg (f32), zero outp, zero deg ----------------
__global__ __launch_bounds__(128) void k_xwg(const float* __restrict__ x,
                                             const float* __restrict__ Wg,
                                             float* __restrict__ xwg,
                                             float* __restrict__ outp,
                                             float* __restrict__ deg) {
  __shared__ float xi[D];
  const int i = blockIdx.x;
  const int t = threadIdx.x;
  xi[t] = x[i * D + t];
  outp[i * D + t] = 0.f;
  if (t == 0) deg[i] = 0.f;
  __syncthreads();
  float acc = 0.f;
#pragma unroll 8
  for (int k = 0; k < D; ++k) acc += xi[k] * Wg[k * D + t];
  xwg[i * D + t] = acc;
}

// ---------------- kernel 2: adjacency via bf16 MFMA + deg atomic ----------------
// grid (256, 2) x 512 threads. Block: 4 i-rows, 512 j (8 chunks of 64).
// LDS 51200B: regionA 32KB (W1^T staging, then xch buf1), regionB 16KB (xch buf0),
// xil 2KB. Double-buffered staging: ONE barrier per chunk.
__global__ __launch_bounds__(512, 2) void k_adj(const float* __restrict__ x,
                                                const float* __restrict__ W1,
                                                const float* __restrict__ b1,
                                                const float* __restrict__ W2,
                                                const float* __restrict__ b2,
                                                float* __restrict__ adj,
                                                float* __restrict__ deg) {
  __shared__ __align__(16) unsigned char smem[51200];
  unsigned char* const regA = smem;            // 32KB
  unsigned char* const regB = smem + 32768;    // 16KB
  float* const xil = (float*)(smem + 49152);   // 4*128 f32

  const int tid  = threadIdx.x;
  const int lane = tid & 63;
  const int w    = tid >> 6;   // wave 0..7
  const int l15  = lane & 15;
  const int g    = lane >> 4;  // 0..3
  const int ibase = blockIdx.x * 4;
  const int jc0   = blockIdx.y * 8;

  // stage W1^T (bf16, swizzled) into regionA
  for (int idx = tid; idx < 128 * 128; idx += 512) {
    const int k = idx >> 7, hid = idx & 127;
    const unsigned short v = f2bf(W1[idx]);
    const int byte = hid * 256 + ((2 * k) ^ ((hid & 7) << 4));
    *(unsigned short*)(regA + byte) = v;
  }
  // stage 4 xi rows (f32, linear)
  {
    const int r = tid >> 7, c = tid & 127;
    xil[tid] = x[(ibase + r) * D + c];
  }
  __syncthreads();

  // preload B fragments into registers: bfrag[ks][ht], k = 32*ks + 8*g + e
  short8 bfrag[4][8];
#pragma unroll
  for (int ks = 0; ks < 4; ++ks)
#pragma unroll
    for (int ht = 0; ht < 8; ++ht) {
      const int hid = ht * 16 + l15;
      const int k0 = ks * 32 + g * 8;
      const int byte = hid * 256 + ((2 * k0) ^ ((hid & 7) << 4));
      bfrag[ks][ht] = *(const short8*)(regA + byte);
    }
  float b1v[8], w2v[8];
#pragma unroll
  for (int ht = 0; ht < 8; ++ht) {
    b1v[ht] = b1[ht * 16 + l15];
    w2v[ht] = W2[ht * 16 + l15];
  }
  const float b2s = b2[0];
  const int jsub = w & 3;

  // stage one 64-row x chunk as bf16 (swizzled) into dst
  auto stage = [&](int jc, unsigned char* dst) {
#pragma unroll
    for (int it = 0; it < 2; ++it) {
      const int row = it * 32 + (tid >> 4);
      const int col = (tid & 15) * 8;
      const float* src = &x[(jc * 64 + row) * D + col];
      const f32x4 v0 = *(const f32x4*)(src);
      const f32x4 v1 = *(const f32x4*)(src + 4);
      short8 pk;
#pragma unroll
      for (int e = 0; e < 4; ++e) pk[e] = (short)f2bf(v0[e]);
#pragma unroll
      for (int e = 0; e < 4; ++e) pk[4 + e] = (short)f2bf(v1[e]);
      const int byte = row * 256 + ((2 * col) ^ ((row & 7) << 4));
      *(short8*)(dst + byte) = pk;
    }
  };

  stage(jc0, regB);          // chunk 0 -> buf0 (regB); regA (bfrag src) untouched
  __syncthreads();           // bfrag reads done + chunk 0 visible

  for (int c = 0; c < 8; ++c) {
    const int jc = jc0 + c;
    unsigned char* const cur = (c & 1) ? regA : regB;
    if (c + 1 < 8) stage(jc + 1, (c & 1) ? regB : regA);  // prefetch next chunk

#pragma unroll
    for (int half = 0; half < 2; ++half) {
      const int iloc = (w >> 2) * 2 + half;
      const int i = ibase + iloc;
      f32x4 acc[8];
#pragma unroll
      for (int ht = 0; ht < 8; ++ht)
        acc[ht] = f32x4{b1v[ht], b1v[ht], b1v[ht], b1v[ht]};

#pragma unroll
      for (int ks = 0; ks < 4; ++ks) {
        const int k0 = ks * 32 + g * 8;
        const f32x4 xa = *(const f32x4*)&xil[iloc * D + k0];
        const f32x4 xb = *(const f32x4*)&xil[iloc * D + k0 + 4];
        const int row = jsub * 16 + l15;
        const int byte = row * 256 + ((2 * k0) ^ ((row & 7) << 4));
        const u32x4 jr = *(const u32x4*)(cur + byte);
        short8 af;
#pragma unroll
        for (int p = 0; p < 4; ++p) {
          const float lo = __builtin_bit_cast(float, jr[p] << 16);
          const float hi = __builtin_bit_cast(float, jr[p] & 0xffff0000u);
          const float xlo = (p < 2) ? xa[2 * p]     : xb[2 * (p - 2)];
          const float xhi = (p < 2) ? xa[2 * p + 1] : xb[2 * (p - 2) + 1];
          af[2 * p]     = (short)f2bf(fabsf(xlo - lo));
          af[2 * p + 1] = (short)f2bf(fabsf(xhi - hi));
        }
#pragma unroll
        for (int ht = 0; ht < 8; ++ht)
          acc[ht] = __builtin_amdgcn_mfma_f32_16x16x32_bf16(af, bfrag[ks][ht],
                                                            acc[ht], 0, 0, 0);
      }
      // epilogue: relu, dot W2, 16-lane reduce, sigmoid, store, deg atomic
      float s0 = 0.f, s1 = 0.f, s2 = 0.f, s3 = 0.f;
#pragma unroll
      for (int ht = 0; ht < 8; ++ht) {
        s0 += fmaxf(acc[ht][0], 0.f) * w2v[ht];
        s1 += fmaxf(acc[ht][1], 0.f) * w2v[ht];
        s2 += fmaxf(acc[ht][2], 0.f) * w2v[ht];
        s3 += fmaxf(acc[ht][3], 0.f) * w2v[ht];
      }
#pragma unroll
      for (int m = 1; m <= 8; m <<= 1) {
        s0 += __shfl_xor(s0, m);
        s1 += __shfl_xor(s1, m);
        s2 += __shfl_xor(s2, m);
        s3 += __shfl_xor(s3, m);
      }
      if (l15 == 0) {
        f32x4 st;
        st[0] = 1.f / (1.f + __expf(-(s0 + b2s)));
        st[1] = 1.f / (1.f + __expf(-(s1 + b2s)));
        st[2] = 1.f / (1.f + __expf(-(s2 + b2s)));
        st[3] = 1.f / (1.f + __expf(-(s3 + b2s)));
        const int j = jc * 64 + jsub * 16 + g * 4;
        *(f32x4*)&adj[i * NPT + j] = st;
        float loc = st[0] + st[1] + st[2] + st[3];
        loc += __shfl_xor(loc, 16);
        loc += __shfl_xor(loc, 32);
        if (lane == 0) atomicAdd(&deg[i], loc);
      }
    }
    __syncthreads();  // chunk c+1 visible; compute on buf[c&1] done
  }
}

// ---------------- kernel 3: partial = sum_j (adj*dinv_j) * xwg, atomic ----------------
__global__ __launch_bounds__(256) void k_d1(const float* __restrict__ adj,
                                            const float* __restrict__ xwg,
                                            const float* __restrict__ deg,
                                            float* __restrict__ outp) {
  __shared__ float ysh[64 * 128];
  __shared__ float anT[64 * 36];
  const int tid = threadIdx.x;
  const int i0 = blockIdx.x * 32;
  const int jbase = blockIdx.y * 128;
  const int iq = tid >> 5;  // 0..7
  const int tq = tid & 31;  // t0 = tq*4
  float acc[4][4];
#pragma unroll
  for (int a = 0; a < 4; ++a)
#pragma unroll
    for (int b = 0; b < 4; ++b) acc[a][b] = 0.f;

  for (int ch = 0; ch < 2; ++ch) {
    const int jb = jbase + ch * 64;
    __syncthreads();
#pragma unroll
    for (int it = 0; it < 8; ++it) {
      const int row = it * 8 + (tid >> 5);
      const int col = (tid & 31) * 4;
      *(f32x4*)&ysh[row * 128 + col] = *(const f32x4*)&xwg[(jb + row) * 128 + col];
    }
    const float dj = rsqrtf(deg[jb + (tid & 63)]);
#pragma unroll
    for (int it = 0; it < 8; ++it) {
      const int ii = it * 4 + (tid >> 6);
      const int jj = tid & 63;
      anT[jj * 36 + ii] = adj[(i0 + ii) * NPT + jb + jj] * dj;
    }
    __syncthreads();
#pragma unroll 4
    for (int jj = 0; jj < 64; ++jj) {
      const f32x4 yv = *(const f32x4*)&ysh[jj * 128 + tq * 4];
      const f32x4 an4 = *(const f32x4*)&anT[jj * 36 + iq * 4];
#pragma unroll
      for (int a = 0; a < 4; ++a)
#pragma unroll
        for (int b = 0; b < 4; ++b) acc[a][b] += an4[a] * yv[b];
    }
  }
#pragma unroll
  for (int a = 0; a < 4; ++a)
#pragma unroll
    for (int b = 0; b < 4; ++b)
      atomicAdd(&outp[(i0 + iq * 4 + a) * D + tq * 4 + b], acc[a][b]);
}

// ---------------- kernel 4: out = leaky(rsqrt(deg_i) * partial + bg) ----------------
__global__ void k_d2(float* __restrict__ outp, const float* __restrict__ deg,
                     const float* __restrict__ bg) {
  const int idx = blockIdx.x * 256 + threadIdx.x;
  const int i = idx >> 7, t = idx & 127;
  const float v = outp[idx] * rsqrtf(deg[i]) + bg[t];
  outp[idx] = v > 0.f ? v : 0.2f * v;
}

extern "C" void kernel_launch(void* const* d_in, const int* in_sizes, int n_in,
                              void* d_out, int out_size, void* d_ws, size_t ws_size,
                              hipStream_t stream) {
  const float* x  = (const float*)d_in[0];
  const float* W1 = (const float*)d_in[1];
  const float* b1 = (const float*)d_in[2];
  const float* W2 = (const float*)d_in[3];
  const float* b2 = (const float*)d_in[4];
  const float* Wg = (const float*)d_in[5];
  const float* bg = (const float*)d_in[6];

  float* outp = (float*)d_out;            // [1024*128]
  float* adj  = outp + NPT * D;           // [1024*1024]
  float* xwg  = (float*)d_ws;             // [1024*128]
  float* deg  = xwg + NPT * D;            // [1024]

  k_xwg<<<NPT, 128, 0, stream>>>(x, Wg, xwg, outp, deg);
  k_adj<<<dim3(256, 2), 512, 0, stream>>>(x, W1, b1, W2, b2, adj, deg);
  k_d1<<<dim3(32, 8), 256, 0, stream>>>(adj, xwg, deg, outp);
  k_d2<<<512, 256, 0, stream>>>(outp, deg, bg);
}

// Round 3
// 85.367 us; speedup vs baseline: 1.2074x; 1.1847x over previous
//
#include <hip/hip_runtime.h>
#include <hip/hip_bf16.h>
#include <math.h>

typedef __attribute__((ext_vector_type(8))) short short8;
typedef __attribute__((ext_vector_type(4))) float f32x4;
typedef __attribute__((ext_vector_type(4))) unsigned int u32x4;

#define NPT 1024
#define D   128

__device__ __forceinline__ unsigned short f2bf(float f) {
  __hip_bfloat16 h = __float2bfloat16(f);
  return __builtin_bit_cast(unsigned short, h);
}

// packed f32->bf16 (RNE) with |.| folded: 1 inst for 2 elements
__device__ __forceinline__ unsigned int cvt_pk_abs(float lo, float hi) {
  unsigned int r;
  asm("v_cvt_pk_bf16_f32 %0, |%1|, |%2|" : "=v"(r) : "v"(lo), "v"(hi));
  return r;
}

// async global->LDS, 16B per lane; lds dest must be wave-uniform base
__device__ __forceinline__ void gload_lds16(const void* g, void* l) {
  __builtin_amdgcn_global_load_lds(
      (const __attribute__((address_space(1))) void*)g,
      (__attribute__((address_space(3))) void*)l, 16, 0, 0);
}

// ---------------- kernel 1: prep (xwg, xsw, w1prep, zero outp/deg) ----------------
// xsw: swizzled bf16 image of x, row r at byte r*256, elem k at ((2k)^((r&7)<<4))
// w1prep: fragment-ordered bf16 W1: frag f=(ks*4+g)*128+hid holds W1[k0..k0+7][hid]
__global__ __launch_bounds__(128) void k_prep(const float* __restrict__ x,
                                              const float* __restrict__ W1,
                                              const float* __restrict__ Wg,
                                              float* __restrict__ xwg,
                                              float* __restrict__ outp,
                                              float* __restrict__ deg,
                                              unsigned short* __restrict__ xsw,
                                              unsigned short* __restrict__ w1prep) {
  __shared__ float xi[D];
  const int i = blockIdx.x;
  const int t = threadIdx.x;
  const float xv = x[i * D + t];
  xi[t] = xv;
  outp[i * D + t] = 0.f;
  if (t == 0) deg[i] = 0.f;
  const int byte = i * 256 + ((2 * t) ^ ((i & 7) << 4));
  *(unsigned short*)((unsigned char*)xsw + byte) = f2bf(xv);
  if (i < 128) {
    // hid = i; thread t supplies k = t
    w1prep[((t >> 3) * 128 + i) * 8 + (t & 7)] = f2bf(W1[t * 128 + i]);
  }
  __syncthreads();
  float acc = 0.f;
#pragma unroll 8
  for (int k = 0; k < D; ++k) acc += xi[k] * Wg[k * D + t];
  xwg[i * D + t] = acc;
}

// ---------------- kernel 2: adjacency via bf16 MFMA + deg atomic ----------------
// grid (256,2) x 512 thr. Block: 4 i-rows, 512 j in 16 chunks of 32.
// LDS: w1L 32KB (fragment-ordered, read per-use) + xb 2x8KB dbuf + xil 2KB = 50KB
__global__ __launch_bounds__(512, 4) void k_adj(const float* __restrict__ x,
                                                const unsigned short* __restrict__ xsw,
                                                const unsigned short* __restrict__ w1prep,
                                                const float* __restrict__ b1,
                                                const float* __restrict__ W2,
                                                const float* __restrict__ b2,
                                                float* __restrict__ adj,
                                                float* __restrict__ deg) {
  __shared__ __align__(16) unsigned char w1L[32768];
  __shared__ __align__(16) unsigned char xb[2][8192];
  __shared__ float xil[4 * 128];

  const int tid  = threadIdx.x;
  const int lane = tid & 63;
  const int w    = tid >> 6;   // wave 0..7
  const int l15  = lane & 15;
  const int g    = lane >> 4;  // 0..3
  const int ibase = blockIdx.x * 4;
  const int jb0   = blockIdx.y * 512;

  // prologue: W1 frags -> LDS (linear copy), chunk0 -> xb[0], xil
#pragma unroll
  for (int q = 0; q < 4; ++q)
    gload_lds16(w1prep + ((q * 8 + w) * 1024 + lane * 16) / 2,
                w1L + (q * 8 + w) * 1024);
  gload_lds16(xsw + (jb0 * 256 + w * 1024 + lane * 16) / 2, xb[0] + w * 1024);
  xil[tid] = x[(ibase + (tid >> 7)) * D + (tid & 127)];
  __syncthreads();

  float b1v[8], w2v[8];
#pragma unroll
  for (int ht = 0; ht < 8; ++ht) {
    b1v[ht] = b1[ht * 16 + l15];
    w2v[ht] = W2[ht * 16 + l15];
  }
  const float b2s = b2[0];

  const int iloc = w >> 1, jsub = w & 1;
  const int i = ibase + iloc;
  const int row = jsub * 16 + l15;
  const int sx = (row & 7) << 4;
  const int xrowbyte = row * 256;

#pragma unroll 1
  for (int c = 0; c < 16; ++c) {
    if (c + 1 < 16)
      gload_lds16(xsw + ((jb0 + (c + 1) * 32) * 256 + w * 1024 + lane * 16) / 2,
                  xb[(c + 1) & 1] + w * 1024);

    const unsigned char* cur = xb[c & 1];
    int w1hold = 0;
    asm volatile("" : "+v"(w1hold));  // defeat cross-chunk hoist of W1 frag reads

    f32x4 acc[8];
#pragma unroll
    for (int ht = 0; ht < 8; ++ht)
      acc[ht] = f32x4{b1v[ht], b1v[ht], b1v[ht], b1v[ht]};

#pragma unroll
    for (int ks = 0; ks < 4; ++ks) {
      const int k0 = ks * 32 + g * 8;
      const f32x4 xa  = *(const f32x4*)&xil[iloc * D + k0];
      const f32x4 xbv = *(const f32x4*)&xil[iloc * D + k0 + 4];
      const u32x4 jr = *(const u32x4*)(cur + xrowbyte + ((2 * k0) ^ sx));
      u32x4 afu;
#pragma unroll
      for (int p = 0; p < 4; ++p) {
        const float lo = __builtin_bit_cast(float, jr[p] << 16);
        const float hi = __builtin_bit_cast(float, jr[p] & 0xffff0000u);
        const float xlo = (p < 2) ? xa[2 * p]     : xbv[2 * (p - 2)];
        const float xhi = (p < 2) ? xa[2 * p + 1] : xbv[2 * (p - 2) + 1];
        afu[p] = cvt_pk_abs(xlo - lo, xhi - hi);
      }
      const short8 af = __builtin_bit_cast(short8, afu);
      const unsigned char* wbase = w1L + (w1hold + (ks * 4 + g) * 2048 + l15 * 16);
#pragma unroll
      for (int ht = 0; ht < 8; ++ht) {
        const short8 bfr = *(const short8*)(wbase + ht * 256);
        acc[ht] = __builtin_amdgcn_mfma_f32_16x16x32_bf16(af, bfr, acc[ht], 0, 0, 0);
      }
    }

    // epilogue: relu, dot W2, 16-lane reduce, sigmoid, store, deg atomic
    float s0 = 0.f, s1 = 0.f, s2 = 0.f, s3 = 0.f;
#pragma unroll
    for (int ht = 0; ht < 8; ++ht) {
      s0 += fmaxf(acc[ht][0], 0.f) * w2v[ht];
      s1 += fmaxf(acc[ht][1], 0.f) * w2v[ht];
      s2 += fmaxf(acc[ht][2], 0.f) * w2v[ht];
      s3 += fmaxf(acc[ht][3], 0.f) * w2v[ht];
    }
#pragma unroll
    for (int m = 1; m <= 8; m <<= 1) {
      s0 += __shfl_xor(s0, m);
      s1 += __shfl_xor(s1, m);
      s2 += __shfl_xor(s2, m);
      s3 += __shfl_xor(s3, m);
    }
    if (l15 == 0) {
      f32x4 st;
      st[0] = 1.f / (1.f + __expf(-(s0 + b2s)));
      st[1] = 1.f / (1.f + __expf(-(s1 + b2s)));
      st[2] = 1.f / (1.f + __expf(-(s2 + b2s)));
      st[3] = 1.f / (1.f + __expf(-(s3 + b2s)));
      const int j = jb0 + c * 32 + jsub * 16 + g * 4;
      *(f32x4*)&adj[i * NPT + j] = st;
      float loc = st[0] + st[1] + st[2] + st[3];
      loc += __shfl_xor(loc, 16);
      loc += __shfl_xor(loc, 32);
      if (lane == 0) atomicAdd(&deg[i], loc);
    }
    __syncthreads();  // drains prefetch vmcnt + protects xb[c&1] for overwrite
  }
}

// ---------------- kernel 3: partial = sum_j (adj*dinv_j) * xwg, atomic ----------------
__global__ __launch_bounds__(256) void k_d1(const float* __restrict__ adj,
                                            const float* __restrict__ xwg,
                                            const float* __restrict__ deg,
                                            float* __restrict__ outp) {
  __shared__ float ysh[64 * 128];
  __shared__ float anT[64 * 36];
  const int tid = threadIdx.x;
  const int i0 = blockIdx.x * 32;
  const int jbase = blockIdx.y * 128;
  const int iq = tid >> 5;
  const int tq = tid & 31;
  float acc[4][4];
#pragma unroll
  for (int a = 0; a < 4; ++a)
#pragma unroll
    for (int b = 0; b < 4; ++b) acc[a][b] = 0.f;

  for (int ch = 0; ch < 2; ++ch) {
    const int jb = jbase + ch * 64;
    __syncthreads();
#pragma unroll
    for (int it = 0; it < 8; ++it) {
      const int rw = it * 8 + (tid >> 5);
      const int cl = (tid & 31) * 4;
      *(f32x4*)&ysh[rw * 128 + cl] = *(const f32x4*)&xwg[(jb + rw) * 128 + cl];
    }
    const float dj = rsqrtf(deg[jb + (tid & 63)]);
#pragma unroll
    for (int it = 0; it < 8; ++it) {
      const int ii = it * 4 + (tid >> 6);
      const int jj = tid & 63;
      anT[jj * 36 + ii] = adj[(i0 + ii) * NPT + jb + jj] * dj;
    }
    __syncthreads();
#pragma unroll 4
    for (int jj = 0; jj < 64; ++jj) {
      const f32x4 yv = *(const f32x4*)&ysh[jj * 128 + tq * 4];
      const f32x4 an4 = *(const f32x4*)&anT[jj * 36 + iq * 4];
#pragma unroll
      for (int a = 0; a < 4; ++a)
#pragma unroll
        for (int b = 0; b < 4; ++b) acc[a][b] += an4[a] * yv[b];
    }
  }
#pragma unroll
  for (int a = 0; a < 4; ++a)
#pragma unroll
    for (int b = 0; b < 4; ++b)
      atomicAdd(&outp[(i0 + iq * 4 + a) * D + tq * 4 + b], acc[a][b]);
}

// ---------------- kernel 4: out = leaky(rsqrt(deg_i) * partial + bg) ----------------
__global__ void k_d2(float* __restrict__ outp, const float* __restrict__ deg,
                     const float* __restrict__ bg) {
  const int idx = blockIdx.x * 256 + threadIdx.x;
  const int i = idx >> 7, t = idx & 127;
  const float v = outp[idx] * rsqrtf(deg[i]) + bg[t];
  outp[idx] = v > 0.f ? v : 0.2f * v;
}

extern "C" void kernel_launch(void* const* d_in, const int* in_sizes, int n_in,
                              void* d_out, int out_size, void* d_ws, size_t ws_size,
                              hipStream_t stream) {
  const float* x  = (const float*)d_in[0];
  const float* W1 = (const float*)d_in[1];
  const float* b1 = (const float*)d_in[2];
  const float* W2 = (const float*)d_in[3];
  const float* b2 = (const float*)d_in[4];
  const float* Wg = (const float*)d_in[5];
  const float* bg = (const float*)d_in[6];

  float* outp = (float*)d_out;              // [1024*128]
  float* adj  = outp + NPT * D;             // [1024*1024]
  float* xwg  = (float*)d_ws;               // [1024*128] f32
  float* deg  = xwg + NPT * D;              // [1024] f32
  unsigned short* xsw    = (unsigned short*)(deg + NPT);   // [1024*128] bf16 swizzled
  unsigned short* w1prep = xsw + NPT * D;                  // [128*128] bf16 frag-ordered

  k_prep<<<NPT, 128, 0, stream>>>(x, W1, Wg, xwg, outp, deg, xsw, w1prep);
  k_adj<<<dim3(256, 2), 512, 0, stream>>>(x, xsw, w1prep, b1, W2, b2, adj, deg);
  k_d1<<<dim3(32, 8), 256, 0, stream>>>(adj, xwg, deg, outp);
  k_d2<<<512, 256, 0, stream>>>(outp, deg, bg);
}